// Round 1
// baseline (1091.358 us; speedup 1.0000x reference)
//
#include <hip/hip_runtime.h>

// HMCEN (no het gate):
//   h_homo = relu(GCN(x, W_homo)); h_het = relu(GCN(x, W_het))
//   out = relu(0.5*(h_homo+h_het) @ W_fuse + b_fuse) @ W_cls + b_cls
//
// Restructured:
//   y[n]   = (x[n] @ [W_homo|W_het]) * dinv[n]          (GEMM, epilogue scale)
//   agg[d] = dinv[d] * (sum_{e:dst=d} y[src_e] + y[d])  (CSR gather, no atomics)
//   out[d] = MLP(relu-combine(agg[d]))                  (fused in gather kernel)
//
// edge_index: JAX has x64 disabled -> int32 on device ("integer -> const int*").

#define IN_DIM 256

// ---------- CSR build ----------
__global__ void count_kernel(const int* __restrict__ dst, int* __restrict__ cnt, int E) {
    int e = blockIdx.x * 256 + threadIdx.x;
    if (e < E) atomicAdd(&cnt[dst[e]], 1);
}

__global__ void dinv_kernel(const int* __restrict__ cnt, float* __restrict__ dinv, int N) {
    int i = blockIdx.x * 256 + threadIdx.x;
    if (i < N) dinv[i] = rsqrtf((float)(cnt[i] + 1));  // +1 self loop; always > 0
}

__global__ __launch_bounds__(1024) void scan_kernel(const int* __restrict__ cnt,
                                                    int* __restrict__ off, int N, int E) {
    __shared__ int part[1024];
    int t = threadIdx.x;
    int per = (N + 1023) >> 10;
    int start = t * per; if (start > N) start = N;
    int end = start + per; if (end > N) end = N;
    int s = 0;
    for (int i = start; i < end; ++i) s += cnt[i];
    part[t] = s;
    __syncthreads();
    for (int d = 1; d < 1024; d <<= 1) {
        int v = (t >= d) ? part[t - d] : 0;
        __syncthreads();
        part[t] += v;
        __syncthreads();
    }
    int run = (t == 0) ? 0 : part[t - 1];
    for (int i = start; i < end; ++i) { off[i] = run; run += cnt[i]; }
    if (t == 1023) off[N] = E;
}

__global__ void fill_kernel(const int* __restrict__ ei, int* __restrict__ cur,
                            const int* __restrict__ off, int* __restrict__ csr, int E) {
    int e = blockIdx.x * 256 + threadIdx.x;
    if (e < E) {
        int s = ei[e];
        int d = ei[E + e];
        int p = atomicAdd(&cur[d], 1);
        csr[off[d] + p] = s;
    }
}

// ---------- GEMM: y = (x @ [W_homo|W_het]) * dinv[row] ----------
// 64x64 tile, BK=32, 256 threads, 4x4 per-thread register tile.
__global__ __launch_bounds__(256) void gemm_kernel(const float* __restrict__ x,
                                                   const float* __restrict__ Wh,
                                                   const float* __restrict__ Wt,
                                                   const float* __restrict__ dinv,
                                                   float* __restrict__ y, int N) {
    __shared__ float xs[32][68];  // transposed: xs[k][m]; stride 68 keeps 16B align, spreads banks
    __shared__ float ws[32][68];
    int tid = threadIdx.x;
    int tx = tid & 15, ty = tid >> 4;
    int rowBase = blockIdx.x * 64;
    int ct = blockIdx.y;                       // 0,1 -> homo cols; 2,3 -> het cols
    const float* __restrict__ W = (ct < 2) ? Wh : Wt;
    int colOff = (ct & 1) * 64;
    int lm = tid >> 3;                         // 0..31 (x tile row)
    int lk = (tid & 7) << 2;                   // 0..28 (x tile k, float4)
    int wk = tid >> 4;                         // 0..15 (W tile k)
    int wc = (tid & 15) << 2;                  // 0..60 (W tile col, float4)
    float acc[4][4] = {};

    for (int k0 = 0; k0 < IN_DIM; k0 += 32) {
#pragma unroll
        for (int half = 0; half < 2; ++half) {
            int row = rowBase + lm + half * 32;
            int rc = row < N ? row : N - 1;
            float4 v = *(const float4*)&x[(size_t)rc * IN_DIM + k0 + lk];
            xs[lk + 0][lm + half * 32] = v.x;
            xs[lk + 1][lm + half * 32] = v.y;
            xs[lk + 2][lm + half * 32] = v.z;
            xs[lk + 3][lm + half * 32] = v.w;
            float4 w4 = *(const float4*)&W[(size_t)(k0 + wk + half * 16) * 128 + colOff + wc];
            *(float4*)&ws[wk + half * 16][wc] = w4;
        }
        __syncthreads();
#pragma unroll
        for (int kk = 0; kk < 32; ++kk) {
            const float4 av = *(const float4*)&xs[kk][ty << 2];
            const float4 bv = *(const float4*)&ws[kk][tx << 2];
            float a_[4] = {av.x, av.y, av.z, av.w};
            float b_[4] = {bv.x, bv.y, bv.z, bv.w};
#pragma unroll
            for (int i = 0; i < 4; ++i)
#pragma unroll
                for (int j = 0; j < 4; ++j) acc[i][j] = fmaf(a_[i], b_[j], acc[i][j]);
        }
        __syncthreads();
    }
#pragma unroll
    for (int i = 0; i < 4; ++i) {
        int row = rowBase + (ty << 2) + i;
        if (row < N) {
            float dv = dinv[row];
            float4 o = make_float4(acc[i][0] * dv, acc[i][1] * dv, acc[i][2] * dv, acc[i][3] * dv);
            *(float4*)&y[(size_t)row * IN_DIM + ct * 64 + (tx << 2)] = o;
        }
    }
}

// ---------- Gather + fused epilogue MLP ----------
// One block (256 threads) per node: thread t owns column t of the 256-dim row.
// W_fuse [128][64] kept in registers: wave w, lane j holds Wf[32w+i][j], i=0..31.
__global__ __launch_bounds__(256) void final_kernel(const float* __restrict__ y,
                                                    const float* __restrict__ dinv,
                                                    const int* __restrict__ off,
                                                    const int* __restrict__ csr,
                                                    const float* __restrict__ b_homo,
                                                    const float* __restrict__ b_het,
                                                    const float* __restrict__ Wf,
                                                    const float* __restrict__ bf,
                                                    const float* __restrict__ Wc,
                                                    const float* __restrict__ bc,
                                                    float* __restrict__ out, int N) {
    __shared__ float rbuf[128];
    __shared__ float fbuf[128];
    __shared__ float hbuf[256];
    __shared__ float wcs[128];
    int tid = threadIdx.x;
    int lane = tid & 63;
    int wid = tid >> 6;

    float wreg[32];
#pragma unroll
    for (int i = 0; i < 32; ++i) wreg[i] = Wf[(size_t)(wid * 32 + i) * 64 + lane];
    if (tid < 128) wcs[tid] = Wc[tid];
    float bvec = (tid < 128) ? b_homo[tid] : b_het[tid - 128];
    float bfv = bf[lane];
    float bc0 = bc[0], bc1 = bc[1];
    __syncthreads();

    for (int n = blockIdx.x; n < N; n += gridDim.x) {
        int e0 = off[n], e1 = off[n + 1];
        float acc = y[(size_t)n * IN_DIM + tid];  // self loop term
        for (int e = e0; e < e1; ++e) {
            int s = csr[e];
            acc += y[(size_t)s * IN_DIM + tid];
        }
        float a = acc * dinv[n] + bvec;
        float r = fmaxf(a, 0.f);
        if (tid >= 128) rbuf[tid - 128] = r;
        __syncthreads();
        if (tid < 128) fbuf[tid] = 0.5f * (r + rbuf[tid]);
        __syncthreads();

        float h = 0.f;
#pragma unroll
        for (int i = 0; i < 32; i += 4) {
            float4 f4 = *(const float4*)&fbuf[wid * 32 + i];
            h = fmaf(f4.x, wreg[i + 0], h);
            h = fmaf(f4.y, wreg[i + 1], h);
            h = fmaf(f4.z, wreg[i + 2], h);
            h = fmaf(f4.w, wreg[i + 3], h);
        }
        hbuf[wid * 64 + lane] = h;
        __syncthreads();
        if (tid < 64) {
            float hh = hbuf[tid] + hbuf[64 + tid] + hbuf[128 + tid] + hbuf[192 + tid] + bfv;
            hh = fmaxf(hh, 0.f);
            float l0 = hh * wcs[tid * 2 + 0];
            float l1 = hh * wcs[tid * 2 + 1];
#pragma unroll
            for (int d = 32; d > 0; d >>= 1) {
                l0 += __shfl_down(l0, d);
                l1 += __shfl_down(l1, d);
            }
            if (tid == 0) {
                out[(size_t)n * 2 + 0] = l0 + bc0;
                out[(size_t)n * 2 + 1] = l1 + bc1;
            }
        }
        __syncthreads();  // protect rbuf/fbuf/hbuf for next iteration
    }
}

extern "C" void kernel_launch(void* const* d_in, const int* in_sizes, int n_in,
                              void* d_out, int out_size, void* d_ws, size_t ws_size,
                              hipStream_t stream) {
    const float* x  = (const float*)d_in[0];
    const int*   ei = (const int*)d_in[1];   // [2,E] int32 (JAX x64 off)
    // d_in[2] = h_node (unused by reference)
    const float* Wh = (const float*)d_in[3];
    const float* bh = (const float*)d_in[4];
    const float* Wt = (const float*)d_in[5];
    const float* bt = (const float*)d_in[6];
    const float* Wf = (const float*)d_in[7];
    const float* bf = (const float*)d_in[8];
    const float* Wc = (const float*)d_in[9];
    const float* bc = (const float*)d_in[10];
    float* out = (float*)d_out;

    int N = in_sizes[0] / IN_DIM;
    int E = in_sizes[1] / 2;

    char* w = (char*)d_ws;
    float* y    = (float*)w;  w += (size_t)N * IN_DIM * 4;
    float* dinv = (float*)w;  w += (size_t)N * 4;
    int*   cnt  = (int*)w;    w += (size_t)N * 4;
    int*   off  = (int*)w;    w += (((size_t)(N + 1) * 4) + 15) & ~(size_t)15;
    int*   cur  = (int*)w;    w += (size_t)N * 4;
    int*   csr  = (int*)w;    w += (size_t)E * 4;

    hipMemsetAsync(cnt, 0, (size_t)N * 4, stream);
    hipMemsetAsync(cur, 0, (size_t)N * 4, stream);

    int eb = (E + 255) / 256;
    int nb = (N + 255) / 256;
    count_kernel<<<eb, 256, 0, stream>>>(ei + E, cnt, E);
    dinv_kernel<<<nb, 256, 0, stream>>>(cnt, dinv, N);
    scan_kernel<<<1, 1024, 0, stream>>>(cnt, off, N, E);
    fill_kernel<<<eb, 256, 0, stream>>>(ei, cur, off, csr, E);

    dim3 ggrid((N + 63) / 64, 4);
    gemm_kernel<<<ggrid, 256, 0, stream>>>(x, Wh, Wt, dinv, y, N);

    final_kernel<<<2048, 256, 0, stream>>>(y, dinv, off, csr, bh, bt, Wf, bf, Wc, bc, out, N);
}

// Round 2
// 585.405 us; speedup vs baseline: 1.8643x; 1.8643x over previous
//
#include <hip/hip_runtime.h>

#define IN_DIM 256   // K of the fused GEMM; also combined hidden (128 homo + 128 het)

typedef __attribute__((ext_vector_type(8))) short short8;
typedef __attribute__((ext_vector_type(4))) float f32x4;
typedef unsigned int uint;
typedef unsigned short ushort;

__device__ __forceinline__ ushort f2bf(float x) {
    uint u = __float_as_uint(x);
    u += 0x7FFFu + ((u >> 16) & 1u);   // round-to-nearest-even
    return (ushort)(u >> 16);
}
__device__ __forceinline__ float bf2f(ushort h) { return __uint_as_float(((uint)h) << 16); }

// ---------- CSR build ----------
__global__ void count_kernel(const int* __restrict__ dst, int* __restrict__ cnt, int E) {
    int e = blockIdx.x * 256 + threadIdx.x;
    if (e < E) atomicAdd(&cnt[dst[e]], 1);
}

__global__ void dinv_kernel(const int* __restrict__ cnt, float* __restrict__ dinv, int N) {
    int i = blockIdx.x * 256 + threadIdx.x;
    if (i < N) dinv[i] = rsqrtf((float)(cnt[i] + 1));  // +1 self loop
}

__global__ __launch_bounds__(1024) void scan_kernel(const int* __restrict__ cnt,
                                                    int* __restrict__ off, int N, int E) {
    __shared__ int part[1024];
    int t = threadIdx.x;
    int per = (N + 1023) >> 10;
    int start = t * per; if (start > N) start = N;
    int end = start + per; if (end > N) end = N;
    int s = 0;
    for (int i = start; i < end; ++i) s += cnt[i];
    part[t] = s;
    __syncthreads();
    for (int d = 1; d < 1024; d <<= 1) {
        int v = (t >= d) ? part[t - d] : 0;
        __syncthreads();
        part[t] += v;
        __syncthreads();
    }
    int run = (t == 0) ? 0 : part[t - 1];
    for (int i = start; i < end; ++i) { off[i] = run; run += cnt[i]; }
    if (t == 1023) off[N] = E;
}

__global__ void fill_kernel(const int* __restrict__ ei, int* __restrict__ cur,
                            const int* __restrict__ off, int* __restrict__ csr, int E) {
    int e = blockIdx.x * 256 + threadIdx.x;
    if (e < E) {
        int s = ei[e];
        int d = ei[E + e];
        int p = atomicAdd(&cur[d], 1);
        csr[off[d] + p] = s;
    }
}

// ---------- W prep: wT[c][k] = bf16(W*[k][c]), c<128 homo, c>=128 het ----------
__global__ void wprep_kernel(const float* __restrict__ Wh, const float* __restrict__ Wt,
                             ushort* __restrict__ wT) {
    int c = blockIdx.x;   // 0..255
    int k = threadIdx.x;  // 0..255
    float v = (c < 128) ? Wh[(size_t)k * 128 + c] : Wt[(size_t)k * 128 + (c - 128)];
    wT[c * 256 + k] = f2bf(v);
}

// ---------- MFMA GEMM: y[n][c] = bf16( (x[n] @ [Wh|Wt])[c] * dinv[n] ) ----------
// Tile BM=128 x BN=256, BK=64, 512 threads (8 waves as 2M x 4N), 16x16x32 bf16 MFMA.
// LDS tiles stored as 16B chunks, XOR-swizzled: chunk(row, kc^(row&7)).
__global__ __launch_bounds__(512) void gemm_kernel(const float* __restrict__ x,
                                                   const ushort* __restrict__ wT,
                                                   const float* __restrict__ dinv,
                                                   ushort* __restrict__ y, int N) {
    __shared__ short As[128 * 64];   // 16 KB
    __shared__ short Bs[256 * 64];   // 32 KB
    int tid = threadIdx.x;
    int lane = tid & 63, wid = tid >> 6;
    int wr = wid >> 2, wc = wid & 3;          // wave sub-tile: 64 rows x 64 cols
    int rowBase = blockIdx.x * 128;

    f32x4 acc[4][4];
#pragma unroll
    for (int a = 0; a < 4; ++a)
#pragma unroll
        for (int b = 0; b < 4; ++b) acc[a][b] = (f32x4){0.f, 0.f, 0.f, 0.f};

    for (int k0 = 0; k0 < IN_DIM; k0 += 64) {
        __syncthreads();
        // stage A: x fp32 -> bf16, 1024 chunks
#pragma unroll
        for (int r = 0; r < 2; ++r) {
            int id = tid + r * 512;
            int m = id >> 3, kc = id & 7;
            int gr = rowBase + m; if (gr >= N) gr = N - 1;
            const float* src = x + (size_t)gr * IN_DIM + k0 + kc * 8;
            float4 v0 = *(const float4*)src;
            float4 v1 = *(const float4*)(src + 4);
            short8 pk;
            pk[0] = (short)f2bf(v0.x); pk[1] = (short)f2bf(v0.y);
            pk[2] = (short)f2bf(v0.z); pk[3] = (short)f2bf(v0.w);
            pk[4] = (short)f2bf(v1.x); pk[5] = (short)f2bf(v1.y);
            pk[6] = (short)f2bf(v1.z); pk[7] = (short)f2bf(v1.w);
            *(short8*)&As[(m * 8 + (kc ^ (m & 7))) * 8] = pk;
        }
        // stage B: wT bf16 copy, 2048 chunks
#pragma unroll
        for (int r = 0; r < 4; ++r) {
            int id = tid + r * 512;
            int n = id >> 3, kc = id & 7;
            short8 v = *(const short8*)(wT + n * 256 + k0 + kc * 8);
            *(short8*)&Bs[(n * 8 + (kc ^ (n & 7))) * 8] = v;
        }
        __syncthreads();

#pragma unroll
        for (int kk = 0; kk < 2; ++kk) {
            int cpos = kk * 4 + (lane >> 4);   // 16B chunk index along K
            short8 af[4], bfr[4];
#pragma unroll
            for (int mf = 0; mf < 4; ++mf) {
                int m = wr * 64 + mf * 16 + (lane & 15);
                af[mf] = *(const short8*)&As[(m * 8 + (cpos ^ (m & 7))) * 8];
            }
#pragma unroll
            for (int nf = 0; nf < 4; ++nf) {
                int n = wc * 64 + nf * 16 + (lane & 15);
                bfr[nf] = *(const short8*)&Bs[(n * 8 + (cpos ^ (n & 7))) * 8];
            }
#pragma unroll
            for (int mf = 0; mf < 4; ++mf)
#pragma unroll
                for (int nf = 0; nf < 4; ++nf)
                    acc[mf][nf] = __builtin_amdgcn_mfma_f32_16x16x32_bf16(
                        af[mf], bfr[nf], acc[mf][nf], 0, 0, 0);
        }
    }

    // epilogue: C/D layout col = lane&15, row = (lane>>4)*4 + reg
#pragma unroll
    for (int mf = 0; mf < 4; ++mf)
#pragma unroll
        for (int i = 0; i < 4; ++i) {
            int row = rowBase + wr * 64 + mf * 16 + ((lane >> 4) << 2) + i;
            if (row < N) {
                float dv = dinv[row];
#pragma unroll
                for (int nf = 0; nf < 4; ++nf)
                    y[(size_t)row * IN_DIM + wc * 64 + nf * 16 + (lane & 15)] =
                        f2bf(acc[mf][nf][i] * dv);
            }
        }
}

// ---------- Gather (wave-per-node, bf16 rows, 2 edges in flight per wave) ----------
// lane layout: slot = lane>>5 (edge parity), g = lane&31 (col group of 8, 16B)
__global__ __launch_bounds__(256) void gather_kernel(const ushort* __restrict__ y,
                                                     const float* __restrict__ dinv,
                                                     const int* __restrict__ off,
                                                     const int* __restrict__ csr,
                                                     const float* __restrict__ bh,
                                                     const float* __restrict__ bt,
                                                     float* __restrict__ f, int N) {
    int tid = threadIdx.x;
    int lane = tid & 63, wid = tid >> 6;
    int slot = lane >> 5, g = lane & 31;
    const float* bsrc = (g < 16) ? (bh + g * 8) : (bt + (g - 16) * 8);
    float bias[8];
    {
        float4 b0 = *(const float4*)bsrc;
        float4 b1 = *(const float4*)(bsrc + 4);
        bias[0] = b0.x; bias[1] = b0.y; bias[2] = b0.z; bias[3] = b0.w;
        bias[4] = b1.x; bias[5] = b1.y; bias[6] = b1.z; bias[7] = b1.w;
    }
    int gw = blockIdx.x * 4 + wid;
    int nw = gridDim.x * 4;

    for (int n = gw; n < N; n += nw) {
        int e0 = off[n], e1 = off[n + 1];
        float a[8] = {0.f, 0.f, 0.f, 0.f, 0.f, 0.f, 0.f, 0.f};
        if (slot == 0) {  // self loop row
            short8 v = *(const short8*)(y + (size_t)n * 256 + g * 8);
#pragma unroll
            for (int j = 0; j < 8; ++j) a[j] = bf2f((ushort)v[j]);
        }
        int e = e0 + slot;
        int s = (e < e1) ? csr[e] : 0;
        while (e < e1) {
            int e2 = e + 2;
            int s2 = (e2 < e1) ? csr[e2] : 0;
            short8 v = *(const short8*)(y + (size_t)s * 256 + g * 8);
#pragma unroll
            for (int j = 0; j < 8; ++j) a[j] += bf2f((ushort)v[j]);
            s = s2; e = e2;
        }
#pragma unroll
        for (int j = 0; j < 8; ++j) a[j] += __shfl_xor(a[j], 32);
        float dv = dinv[n];
        float r[8];
#pragma unroll
        for (int j = 0; j < 8; ++j) r[j] = fmaxf(fmaf(a[j], dv, bias[j]), 0.f);
#pragma unroll
        for (int j = 0; j < 8; ++j) {
            float o = __shfl_xor(r[j], 16);     // partner homo<->het group
            r[j] = 0.5f * (r[j] + o);
        }
        if (lane < 16) {  // slot==0 && g<16 -> write fused 128-dim row
            float4 w0 = make_float4(r[0], r[1], r[2], r[3]);
            float4 w1 = make_float4(r[4], r[5], r[6], r[7]);
            float* dst = f + (size_t)n * 128 + g * 8;
            *(float4*)dst = w0;
            *(float4*)(dst + 4) = w1;
        }
    }
}

// ---------- MLP: out = relu(f @ Wf + bf) @ Wc + bc ----------
// 4 nodes per block-iteration (one per wave); Wf staged in LDS [128][64].
__global__ __launch_bounds__(256) void mlp_kernel(const float* __restrict__ f,
                                                  const float* __restrict__ Wf,
                                                  const float* __restrict__ bfu,
                                                  const float* __restrict__ Wc,
                                                  const float* __restrict__ bc,
                                                  float* __restrict__ out, int N) {
    __shared__ float WfL[128 * 64];
    __shared__ float fb[4][128];
    int tid = threadIdx.x;
    int lane = tid & 63;
    int sub = tid >> 6;
#pragma unroll
    for (int i = 0; i < 32; ++i) WfL[tid + i * 256] = Wf[tid + i * 256];
    float bfv = bfu[lane];
    float wc0 = Wc[lane * 2], wc1 = Wc[lane * 2 + 1];
    float bc0 = bc[0], bc1 = bc[1];
    __syncthreads();

    for (int n0 = blockIdx.x * 4; n0 < N; n0 += gridDim.x * 4) {
        __syncthreads();
#pragma unroll
        for (int i = 0; i < 2; ++i) {
            int e = tid + i * 256;               // 512 floats = 4 rows
            fb[e >> 7][e & 127] = f[(size_t)n0 * 128 + e];
        }
        __syncthreads();
        float h = 0.f;
#pragma unroll
        for (int c = 0; c < 128; c += 4) {
            float4 fv = *(const float4*)&fb[sub][c];   // wave-uniform -> broadcast
            h = fmaf(fv.x, WfL[(c + 0) * 64 + lane], h);
            h = fmaf(fv.y, WfL[(c + 1) * 64 + lane], h);
            h = fmaf(fv.z, WfL[(c + 2) * 64 + lane], h);
            h = fmaf(fv.w, WfL[(c + 3) * 64 + lane], h);
        }
        float hh = fmaxf(h + bfv, 0.f);
        float p0 = hh * wc0, p1 = hh * wc1;
#pragma unroll
        for (int d = 32; d > 0; d >>= 1) {
            p0 += __shfl_xor(p0, d);
            p1 += __shfl_xor(p1, d);
        }
        if (lane == 0) {
            int n = n0 + sub;
            out[(size_t)n * 2 + 0] = p0 + bc0;
            out[(size_t)n * 2 + 1] = p1 + bc1;
        }
    }
}

extern "C" void kernel_launch(void* const* d_in, const int* in_sizes, int n_in,
                              void* d_out, int out_size, void* d_ws, size_t ws_size,
                              hipStream_t stream) {
    const float* x  = (const float*)d_in[0];
    const int*   ei = (const int*)d_in[1];   // [2,E] int32
    const float* Wh = (const float*)d_in[3];
    const float* bh = (const float*)d_in[4];
    const float* Wt = (const float*)d_in[5];
    const float* bt = (const float*)d_in[6];
    const float* Wf = (const float*)d_in[7];
    const float* bf_ = (const float*)d_in[8];
    const float* Wc = (const float*)d_in[9];
    const float* bc = (const float*)d_in[10];
    float* out = (float*)d_out;

    int N = in_sizes[0] / IN_DIM;
    int E = in_sizes[1] / 2;

    char* w = (char*)d_ws;
    ushort* y   = (ushort*)w;  w += (size_t)N * IN_DIM * 2;          // 51.2 MB bf16
    ushort* wT  = (ushort*)w;  w += (size_t)256 * 256 * 2;           // 128 KB
    float*  f   = (float*)w;   w += (size_t)N * 128 * 4;             // 51.2 MB
    float* dinv = (float*)w;   w += (size_t)N * 4;
    int*   cnt  = (int*)w;     w += (size_t)N * 4;
    int*   off  = (int*)w;     w += (((size_t)(N + 1) * 4) + 15) & ~(size_t)15;
    int*   cur  = (int*)w;     w += (size_t)N * 4;
    int*   csr  = (int*)w;     w += (size_t)E * 4;

    hipMemsetAsync(cnt, 0, (size_t)N * 4, stream);
    hipMemsetAsync(cur, 0, (size_t)N * 4, stream);

    int eb = (E + 255) / 256;
    int nb = (N + 255) / 256;
    count_kernel<<<eb, 256, 0, stream>>>(ei + E, cnt, E);
    dinv_kernel<<<nb, 256, 0, stream>>>(cnt, dinv, N);
    scan_kernel<<<1, 1024, 0, stream>>>(cnt, off, N, E);
    fill_kernel<<<eb, 256, 0, stream>>>(ei, cur, off, csr, E);
    wprep_kernel<<<256, 256, 0, stream>>>(Wh, Wt, wT);

    gemm_kernel<<<(N + 127) / 128, 512, 0, stream>>>(x, wT, dinv, y, N);
    gather_kernel<<<2048, 256, 0, stream>>>(y, dinv, off, csr, bh, bt, f, N);
    mlp_kernel<<<1024, 256, 0, stream>>>(f, Wf, bf_, Wc, bc, out, N);
}

// Round 3
// 369.280 us; speedup vs baseline: 2.9554x; 1.5853x over previous
//
#include <hip/hip_runtime.h>

#define IN_DIM 256   // K of the fused GEMM; also combined hidden (128 homo + 128 het)

typedef __attribute__((ext_vector_type(8))) short short8;
typedef __attribute__((ext_vector_type(4))) float f32x4;
typedef unsigned int uint;
typedef unsigned short ushort;

__device__ __forceinline__ ushort f2bf(float x) {
    uint u = __float_as_uint(x);
    u += 0x7FFFu + ((u >> 16) & 1u);   // round-to-nearest-even
    return (ushort)(u >> 16);
}
__device__ __forceinline__ float bf2f(ushort h) { return __uint_as_float(((uint)h) << 16); }

// ---------- CSR build ----------
__global__ void count_kernel(const int* __restrict__ dst, int* __restrict__ cnt, int E) {
    int e = blockIdx.x * 256 + threadIdx.x;
    if (e < E) atomicAdd(&cnt[dst[e]], 1);
}

// Phase 1: per-block sums of 1024-count chunks
__global__ __launch_bounds__(256) void block_sum_kernel(const int* __restrict__ cnt,
                                                        int* __restrict__ bsum, int N) {
    __shared__ int red[256];
    int base = blockIdx.x * 1024;
    int s = 0;
    for (int i = threadIdx.x; i < 1024; i += 256) {
        int idx = base + i;
        if (idx < N) s += cnt[idx];
    }
    red[threadIdx.x] = s;
    __syncthreads();
    for (int d = 128; d > 0; d >>= 1) {
        if (threadIdx.x < d) red[threadIdx.x] += red[threadIdx.x + d];
        __syncthreads();
    }
    if (threadIdx.x == 0) bsum[blockIdx.x] = red[0];
}

// Phase 2: exclusive scan of block sums (B <= 1024), single block
__global__ __launch_bounds__(1024) void scan_sums_kernel(int* __restrict__ bsum, int B) {
    __shared__ int sh[1024];
    int t = threadIdx.x;
    sh[t] = (t < B) ? bsum[t] : 0;
    __syncthreads();
    for (int d = 1; d < 1024; d <<= 1) {
        int v = (t >= d) ? sh[t - d] : 0;
        __syncthreads();
        sh[t] += v;
        __syncthreads();
    }
    if (t < B) bsum[t] = (t == 0) ? 0 : sh[t - 1];
}

// Phase 3: per-chunk exclusive scan + write offsets; dinv fused
__global__ __launch_bounds__(256) void scan_out_kernel(const int* __restrict__ cnt,
                                                       const int* __restrict__ bsum,
                                                       int* __restrict__ off,
                                                       float* __restrict__ dinv,
                                                       int N, int E) {
    __shared__ int wsum[4];
    int lane = threadIdx.x & 63, wid = threadIdx.x >> 6;
    int idx = blockIdx.x * 1024 + threadIdx.x * 4;
    int c[4];
    int s = 0;
#pragma unroll
    for (int j = 0; j < 4; ++j) {
        c[j] = (idx + j < N) ? cnt[idx + j] : 0;
        s += c[j];
    }
    int incl = s;
#pragma unroll
    for (int d = 1; d < 64; d <<= 1) {
        int v = __shfl_up(incl, d);
        if (lane >= d) incl += v;
    }
    if (lane == 63) wsum[wid] = incl;
    __syncthreads();
    int woff = 0;
    for (int i = 0; i < 4; ++i) woff += (i < wid) ? wsum[i] : 0;
    int excl = bsum[blockIdx.x] + woff + incl - s;
#pragma unroll
    for (int j = 0; j < 4; ++j) {
        if (idx + j < N) {
            off[idx + j] = excl;
            dinv[idx + j] = rsqrtf((float)(c[j] + 1));  // +1 self loop
        }
        excl += c[j];
    }
    if (blockIdx.x == 0 && threadIdx.x == 0) off[N] = E;
}

__global__ void fill_kernel(const int* __restrict__ ei, int* __restrict__ cur,
                            const int* __restrict__ off, int* __restrict__ csr, int E) {
    int e = blockIdx.x * 256 + threadIdx.x;
    if (e < E) {
        int s = ei[e];
        int d = ei[E + e];
        int p = atomicAdd(&cur[d], 1);
        csr[off[d] + p] = s;
    }
}

// ---------- W prep ----------
__global__ void wprep_kernel(const float* __restrict__ Wh, const float* __restrict__ Wt,
                             ushort* __restrict__ wT) {
    int c = blockIdx.x;   // 0..255
    int k = threadIdx.x;  // 0..255
    float v = (c < 128) ? Wh[(size_t)k * 128 + c] : Wt[(size_t)k * 128 + (c - 128)];
    wT[c * 256 + k] = f2bf(v);
}

// WfB[col][k] = bf16(Wf[k][col])  (B-operand for the MLP MFMA)
__global__ void wfb_kernel(const float* __restrict__ Wf, ushort* __restrict__ WfB) {
    int col = blockIdx.x;   // 0..63
    int k = threadIdx.x;    // 0..127
    WfB[col * 128 + k] = f2bf(Wf[(size_t)k * 64 + col]);
}

// ---------- MFMA GEMM: y[n][c] = bf16( (x[n] @ [Wh|Wt])[c] * dinv[n] ) ----------
__global__ __launch_bounds__(512) void gemm_kernel(const float* __restrict__ x,
                                                   const ushort* __restrict__ wT,
                                                   const float* __restrict__ dinv,
                                                   ushort* __restrict__ y, int N) {
    __shared__ short As[128 * 64];   // 16 KB
    __shared__ short Bs[256 * 64];   // 32 KB
    int tid = threadIdx.x;
    int lane = tid & 63, wid = tid >> 6;
    int wr = wid >> 2, wc = wid & 3;
    int rowBase = blockIdx.x * 128;

    f32x4 acc[4][4];
#pragma unroll
    for (int a = 0; a < 4; ++a)
#pragma unroll
        for (int b = 0; b < 4; ++b) acc[a][b] = (f32x4){0.f, 0.f, 0.f, 0.f};

    for (int k0 = 0; k0 < IN_DIM; k0 += 64) {
        __syncthreads();
#pragma unroll
        for (int r = 0; r < 2; ++r) {
            int id = tid + r * 512;
            int m = id >> 3, kc = id & 7;
            int gr = rowBase + m; if (gr >= N) gr = N - 1;
            const float* src = x + (size_t)gr * IN_DIM + k0 + kc * 8;
            float4 v0 = *(const float4*)src;
            float4 v1 = *(const float4*)(src + 4);
            short8 pk;
            pk[0] = (short)f2bf(v0.x); pk[1] = (short)f2bf(v0.y);
            pk[2] = (short)f2bf(v0.z); pk[3] = (short)f2bf(v0.w);
            pk[4] = (short)f2bf(v1.x); pk[5] = (short)f2bf(v1.y);
            pk[6] = (short)f2bf(v1.z); pk[7] = (short)f2bf(v1.w);
            *(short8*)&As[(m * 8 + (kc ^ (m & 7))) * 8] = pk;
        }
#pragma unroll
        for (int r = 0; r < 4; ++r) {
            int id = tid + r * 512;
            int n = id >> 3, kc = id & 7;
            short8 v = *(const short8*)(wT + n * 256 + k0 + kc * 8);
            *(short8*)&Bs[(n * 8 + (kc ^ (n & 7))) * 8] = v;
        }
        __syncthreads();

#pragma unroll
        for (int kk = 0; kk < 2; ++kk) {
            int cpos = kk * 4 + (lane >> 4);
            short8 af[4], bfr[4];
#pragma unroll
            for (int mf = 0; mf < 4; ++mf) {
                int m = wr * 64 + mf * 16 + (lane & 15);
                af[mf] = *(const short8*)&As[(m * 8 + (cpos ^ (m & 7))) * 8];
            }
#pragma unroll
            for (int nf = 0; nf < 4; ++nf) {
                int n = wc * 64 + nf * 16 + (lane & 15);
                bfr[nf] = *(const short8*)&Bs[(n * 8 + (cpos ^ (n & 7))) * 8];
            }
#pragma unroll
            for (int mf = 0; mf < 4; ++mf)
#pragma unroll
                for (int nf = 0; nf < 4; ++nf)
                    acc[mf][nf] = __builtin_amdgcn_mfma_f32_16x16x32_bf16(
                        af[mf], bfr[nf], acc[mf][nf], 0, 0, 0);
        }
    }

#pragma unroll
    for (int mf = 0; mf < 4; ++mf)
#pragma unroll
        for (int i = 0; i < 4; ++i) {
            int row = rowBase + wr * 64 + mf * 16 + ((lane >> 4) << 2) + i;
            if (row < N) {
                float dv = dinv[row];
#pragma unroll
                for (int nf = 0; nf < 4; ++nf)
                    y[(size_t)row * IN_DIM + wc * 64 + nf * 16 + (lane & 15)] =
                        f2bf(acc[mf][nf][i] * dv);
            }
        }
}

// ---------- Gather (wave-per-node, bf16 rows, 2 edges in flight) ----------
__global__ __launch_bounds__(256) void gather_kernel(const ushort* __restrict__ y,
                                                     const float* __restrict__ dinv,
                                                     const int* __restrict__ off,
                                                     const int* __restrict__ csr,
                                                     const float* __restrict__ bh,
                                                     const float* __restrict__ bt,
                                                     ushort* __restrict__ f, int N) {
    int tid = threadIdx.x;
    int lane = tid & 63, wid = tid >> 6;
    int slot = lane >> 5, g = lane & 31;
    const float* bsrc = (g < 16) ? (bh + g * 8) : (bt + (g - 16) * 8);
    float bias[8];
    {
        float4 b0 = *(const float4*)bsrc;
        float4 b1 = *(const float4*)(bsrc + 4);
        bias[0] = b0.x; bias[1] = b0.y; bias[2] = b0.z; bias[3] = b0.w;
        bias[4] = b1.x; bias[5] = b1.y; bias[6] = b1.z; bias[7] = b1.w;
    }
    int gw = blockIdx.x * 4 + wid;
    int nw = gridDim.x * 4;

    for (int n = gw; n < N; n += nw) {
        int e0 = off[n], e1 = off[n + 1];
        float a[8] = {0.f, 0.f, 0.f, 0.f, 0.f, 0.f, 0.f, 0.f};
        if (slot == 0) {
            short8 v = *(const short8*)(y + (size_t)n * 256 + g * 8);
#pragma unroll
            for (int j = 0; j < 8; ++j) a[j] = bf2f((ushort)v[j]);
        }
        int e = e0 + slot;
        int s = (e < e1) ? csr[e] : 0;
        while (e < e1) {
            int e2 = e + 2;
            int s2 = (e2 < e1) ? csr[e2] : 0;
            short8 v = *(const short8*)(y + (size_t)s * 256 + g * 8);
#pragma unroll
            for (int j = 0; j < 8; ++j) a[j] += bf2f((ushort)v[j]);
            s = s2; e = e2;
        }
#pragma unroll
        for (int j = 0; j < 8; ++j) a[j] += __shfl_xor(a[j], 32);
        float dv = dinv[n];
        float r[8];
#pragma unroll
        for (int j = 0; j < 8; ++j) r[j] = fmaxf(fmaf(a[j], dv, bias[j]), 0.f);
#pragma unroll
        for (int j = 0; j < 8; ++j) {
            float o = __shfl_xor(r[j], 16);
            r[j] = 0.5f * (r[j] + o);
        }
        if (lane < 16) {
            short8 pk;
#pragma unroll
            for (int j = 0; j < 8; ++j) pk[j] = (short)f2bf(r[j]);
            *(short8*)(f + (size_t)n * 128 + g * 8) = pk;
        }
    }
}

// ---------- MFMA MLP: out = relu(f @ Wf + bf) @ Wc + bc ----------
// Wave per 16 nodes; A/B frags straight from global (no LDS); classifier in epilogue.
__global__ __launch_bounds__(256) void mlp_kernel(const ushort* __restrict__ f,
                                                  const ushort* __restrict__ WfB,
                                                  const float* __restrict__ bfu,
                                                  const float* __restrict__ Wc,
                                                  const float* __restrict__ bc,
                                                  float* __restrict__ out, int N) {
    int tid = threadIdx.x;
    int lane = tid & 63, wid = tid >> 6;
    int rowBase = blockIdx.x * 64 + wid * 16;
    int col = lane & 15;
    int kg = lane >> 4;

    short8 bfrag[4][4];
#pragma unroll
    for (int nf = 0; nf < 4; ++nf)
#pragma unroll
        for (int kk = 0; kk < 4; ++kk)
            bfrag[nf][kk] = *(const short8*)(WfB + (size_t)(nf * 16 + col) * 128 + kk * 32 + kg * 8);

    float bfv[4], w0[4], w1[4];
#pragma unroll
    for (int nf = 0; nf < 4; ++nf) {
        int c = nf * 16 + col;
        bfv[nf] = bfu[c];
        w0[nf] = Wc[c * 2];
        w1[nf] = Wc[c * 2 + 1];
    }
    float bc0 = bc[0], bc1 = bc[1];

    int r = rowBase + col; if (r >= N) r = N - 1;
    f32x4 acc[4];
#pragma unroll
    for (int nf = 0; nf < 4; ++nf) acc[nf] = (f32x4){0.f, 0.f, 0.f, 0.f};
#pragma unroll
    for (int kk = 0; kk < 4; ++kk) {
        short8 afrag = *(const short8*)(f + (size_t)r * 128 + kk * 32 + kg * 8);
#pragma unroll
        for (int nf = 0; nf < 4; ++nf)
            acc[nf] = __builtin_amdgcn_mfma_f32_16x16x32_bf16(afrag, bfrag[nf][kk], acc[nf], 0, 0, 0);
    }

#pragma unroll
    for (int i = 0; i < 4; ++i) {
        float p0 = 0.f, p1 = 0.f;
#pragma unroll
        for (int nf = 0; nf < 4; ++nf) {
            float t = fmaxf(acc[nf][i] + bfv[nf], 0.f);
            p0 = fmaf(t, w0[nf], p0);
            p1 = fmaf(t, w1[nf], p1);
        }
#pragma unroll
        for (int d = 1; d < 16; d <<= 1) {
            p0 += __shfl_xor(p0, d);
            p1 += __shfl_xor(p1, d);
        }
        int row = rowBase + kg * 4 + i;
        if (col == 0 && row < N)
            *(float2*)(out + (size_t)row * 2) = make_float2(p0 + bc0, p1 + bc1);
    }
}

extern "C" void kernel_launch(void* const* d_in, const int* in_sizes, int n_in,
                              void* d_out, int out_size, void* d_ws, size_t ws_size,
                              hipStream_t stream) {
    const float* x  = (const float*)d_in[0];
    const int*   ei = (const int*)d_in[1];   // [2,E] int32
    const float* Wh = (const float*)d_in[3];
    const float* bh = (const float*)d_in[4];
    const float* Wt = (const float*)d_in[5];
    const float* bt = (const float*)d_in[6];
    const float* Wf = (const float*)d_in[7];
    const float* bf_ = (const float*)d_in[8];
    const float* Wc = (const float*)d_in[9];
    const float* bc = (const float*)d_in[10];
    float* out = (float*)d_out;

    int N = in_sizes[0] / IN_DIM;
    int E = in_sizes[1] / 2;
    int B = (N + 1023) / 1024;   // scan chunks

    char* w = (char*)d_ws;
    ushort* y   = (ushort*)w;  w += (size_t)N * IN_DIM * 2;          // 51.2 MB bf16
    ushort* wT  = (ushort*)w;  w += (size_t)256 * 256 * 2;
    ushort* WfB = (ushort*)w;  w += (size_t)64 * 128 * 2;
    ushort* f   = (ushort*)w;  w += (size_t)N * 128 * 2;             // 25.6 MB bf16
    float* dinv = (float*)w;   w += (size_t)N * 4;
    int*   cnt  = (int*)w;     w += (size_t)N * 4;
    int*   off  = (int*)w;     w += (((size_t)(N + 1) * 4) + 15) & ~(size_t)15;
    int*   cur  = (int*)w;     w += (size_t)N * 4;
    int*   bsum = (int*)w;     w += (((size_t)B * 4) + 15) & ~(size_t)15;
    int*   csr  = (int*)w;     w += (size_t)E * 4;

    hipMemsetAsync(cnt, 0, (size_t)N * 4, stream);
    hipMemsetAsync(cur, 0, (size_t)N * 4, stream);

    int eb = (E + 255) / 256;
    count_kernel<<<eb, 256, 0, stream>>>(ei + E, cnt, E);
    block_sum_kernel<<<B, 256, 0, stream>>>(cnt, bsum, N);
    scan_sums_kernel<<<1, 1024, 0, stream>>>(bsum, B);
    scan_out_kernel<<<B, 256, 0, stream>>>(cnt, bsum, off, dinv, N, E);
    fill_kernel<<<eb, 256, 0, stream>>>(ei, cur, off, csr, E);
    wprep_kernel<<<256, 256, 0, stream>>>(Wh, Wt, wT);
    wfb_kernel<<<64, 128, 0, stream>>>(Wf, WfB);

    gemm_kernel<<<(N + 127) / 128, 512, 0, stream>>>(x, wT, dinv, y, N);
    gather_kernel<<<2048, 256, 0, stream>>>(y, dinv, off, csr, bh, bt, f, N);
    mlp_kernel<<<(N + 63) / 64, 256, 0, stream>>>(f, WfB, bf_, Wc, bc, out, N);
}

// Round 4
// 361.476 us; speedup vs baseline: 3.0192x; 1.0216x over previous
//
#include <hip/hip_runtime.h>

#define IN_DIM 256   // K of the fused GEMM; also combined hidden (128 homo + 128 het)

typedef __attribute__((ext_vector_type(8))) short short8;
typedef __attribute__((ext_vector_type(4))) float f32x4;
typedef unsigned int uint;
typedef unsigned short ushort;

__device__ __forceinline__ ushort f2bf(float x) {
    uint u = __float_as_uint(x);
    u += 0x7FFFu + ((u >> 16) & 1u);   // round-to-nearest-even
    return (ushort)(u >> 16);
}

// ---------- CSR build ----------
__global__ void count_kernel(const int* __restrict__ dst, int* __restrict__ cnt, int E) {
    int e = blockIdx.x * 256 + threadIdx.x;
    if (e < E) atomicAdd(&cnt[dst[e]], 1);
}

// Phase 1: per-block sums of 1024-count chunks
__global__ __launch_bounds__(256) void block_sum_kernel(const int* __restrict__ cnt,
                                                        int* __restrict__ bsum, int N) {
    __shared__ int red[256];
    int base = blockIdx.x * 1024;
    int s = 0;
    for (int i = threadIdx.x; i < 1024; i += 256) {
        int idx = base + i;
        if (idx < N) s += cnt[idx];
    }
    red[threadIdx.x] = s;
    __syncthreads();
    for (int d = 128; d > 0; d >>= 1) {
        if (threadIdx.x < d) red[threadIdx.x] += red[threadIdx.x + d];
        __syncthreads();
    }
    if (threadIdx.x == 0) bsum[blockIdx.x] = red[0];
}

// Phase 2: exclusive scan of block sums (B <= 1024), single block
__global__ __launch_bounds__(1024) void scan_sums_kernel(int* __restrict__ bsum, int B) {
    __shared__ int sh[1024];
    int t = threadIdx.x;
    sh[t] = (t < B) ? bsum[t] : 0;
    __syncthreads();
    for (int d = 1; d < 1024; d <<= 1) {
        int v = (t >= d) ? sh[t - d] : 0;
        __syncthreads();
        sh[t] += v;
        __syncthreads();
    }
    if (t < B) bsum[t] = (t == 0) ? 0 : sh[t - 1];
}

// Phase 3: per-chunk exclusive scan + write offsets; dinv fused
__global__ __launch_bounds__(256) void scan_out_kernel(const int* __restrict__ cnt,
                                                       const int* __restrict__ bsum,
                                                       int* __restrict__ off,
                                                       float* __restrict__ dinv,
                                                       int N, int E) {
    __shared__ int wsum[4];
    int lane = threadIdx.x & 63, wid = threadIdx.x >> 6;
    int idx = blockIdx.x * 1024 + threadIdx.x * 4;
    int c[4];
    int s = 0;
#pragma unroll
    for (int j = 0; j < 4; ++j) {
        c[j] = (idx + j < N) ? cnt[idx + j] : 0;
        s += c[j];
    }
    int incl = s;
#pragma unroll
    for (int d = 1; d < 64; d <<= 1) {
        int v = __shfl_up(incl, d);
        if (lane >= d) incl += v;
    }
    if (lane == 63) wsum[wid] = incl;
    __syncthreads();
    int woff = 0;
    for (int i = 0; i < 4; ++i) woff += (i < wid) ? wsum[i] : 0;
    int excl = bsum[blockIdx.x] + woff + incl - s;
#pragma unroll
    for (int j = 0; j < 4; ++j) {
        if (idx + j < N) {
            off[idx + j] = excl;
            dinv[idx + j] = rsqrtf((float)(c[j] + 1));  // +1 self loop
        }
        excl += c[j];
    }
    if (blockIdx.x == 0 && threadIdx.x == 0) off[N] = E;
}

__global__ void fill_kernel(const int* __restrict__ ei, int* __restrict__ cur,
                            const int* __restrict__ off, int* __restrict__ csr, int E) {
    int e = blockIdx.x * 256 + threadIdx.x;
    if (e < E) {
        int s = ei[e];
        int d = ei[E + e];
        int p = atomicAdd(&cur[d], 1);
        csr[off[d] + p] = s;
    }
}

// ---------- W prep ----------
__global__ void wprep_kernel(const float* __restrict__ Wh, const float* __restrict__ Wt,
                             ushort* __restrict__ wT) {
    int c = blockIdx.x;   // 0..255
    int k = threadIdx.x;  // 0..255
    float v = (c < 128) ? Wh[(size_t)k * 128 + c] : Wt[(size_t)k * 128 + (c - 128)];
    wT[c * 256 + k] = f2bf(v);
}

// WfB[col][k] = bf16(Wf[k][col])
__global__ void wfb_kernel(const float* __restrict__ Wf, ushort* __restrict__ WfB) {
    int col = blockIdx.x;   // 0..63
    int k = threadIdx.x;    // 0..127
    WfB[col * 128 + k] = f2bf(Wf[(size_t)k * 64 + col]);
}

// ---------- MFMA GEMM: y[n][c] = bf16( (x[n] @ [Wh|Wt])[c] * dinv[n] ) ----------
__global__ __launch_bounds__(512) void gemm_kernel(const float* __restrict__ x,
                                                   const ushort* __restrict__ wT,
                                                   const float* __restrict__ dinv,
                                                   ushort* __restrict__ y, int N) {
    __shared__ short As[128 * 64];   // 16 KB
    __shared__ short Bs[256 * 64];   // 32 KB
    int tid = threadIdx.x;
    int lane = tid & 63, wid = tid >> 6;
    int wr = wid >> 2, wc = wid & 3;
    int rowBase = blockIdx.x * 128;

    f32x4 acc[4][4];
#pragma unroll
    for (int a = 0; a < 4; ++a)
#pragma unroll
        for (int b = 0; b < 4; ++b) acc[a][b] = (f32x4){0.f, 0.f, 0.f, 0.f};

    for (int k0 = 0; k0 < IN_DIM; k0 += 64) {
        __syncthreads();
#pragma unroll
        for (int r = 0; r < 2; ++r) {
            int id = tid + r * 512;
            int m = id >> 3, kc = id & 7;
            int gr = rowBase + m; if (gr >= N) gr = N - 1;
            const float* src = x + (size_t)gr * IN_DIM + k0 + kc * 8;
            float4 v0 = *(const float4*)src;
            float4 v1 = *(const float4*)(src + 4);
            short8 pk;
            pk[0] = (short)f2bf(v0.x); pk[1] = (short)f2bf(v0.y);
            pk[2] = (short)f2bf(v0.z); pk[3] = (short)f2bf(v0.w);
            pk[4] = (short)f2bf(v1.x); pk[5] = (short)f2bf(v1.y);
            pk[6] = (short)f2bf(v1.z); pk[7] = (short)f2bf(v1.w);
            *(short8*)&As[(m * 8 + (kc ^ (m & 7))) * 8] = pk;
        }
#pragma unroll
        for (int r = 0; r < 4; ++r) {
            int id = tid + r * 512;
            int n = id >> 3, kc = id & 7;
            short8 v = *(const short8*)(wT + n * 256 + k0 + kc * 8);
            *(short8*)&Bs[(n * 8 + (kc ^ (n & 7))) * 8] = v;
        }
        __syncthreads();

#pragma unroll
        for (int kk = 0; kk < 2; ++kk) {
            int cpos = kk * 4 + (lane >> 4);
            short8 af[4], bfr[4];
#pragma unroll
            for (int mf = 0; mf < 4; ++mf) {
                int m = wr * 64 + mf * 16 + (lane & 15);
                af[mf] = *(const short8*)&As[(m * 8 + (cpos ^ (m & 7))) * 8];
            }
#pragma unroll
            for (int nf = 0; nf < 4; ++nf) {
                int n = wc * 64 + nf * 16 + (lane & 15);
                bfr[nf] = *(const short8*)&Bs[(n * 8 + (cpos ^ (n & 7))) * 8];
            }
#pragma unroll
            for (int mf = 0; mf < 4; ++mf)
#pragma unroll
                for (int nf = 0; nf < 4; ++nf)
                    acc[mf][nf] = __builtin_amdgcn_mfma_f32_16x16x32_bf16(
                        af[mf], bfr[nf], acc[mf][nf], 0, 0, 0);
        }
    }

#pragma unroll
    for (int mf = 0; mf < 4; ++mf)
#pragma unroll
        for (int i = 0; i < 4; ++i) {
            int row = rowBase + wr * 64 + mf * 16 + ((lane >> 4) << 2) + i;
            if (row < N) {
                float dv = dinv[row];
#pragma unroll
                for (int nf = 0; nf < 4; ++nf)
                    y[(size_t)row * IN_DIM + wc * 64 + nf * 16 + (lane & 15)] =
                        f2bf(acc[mf][nf][i] * dv);
            }
        }
}

// ---------- Gather (wave-per-node; whole-wave rows; 4 edges in flight) ----------
// Lane owns 4 dims: c = lane*4 + j. Edge indices fetched coalesced, broadcast
// via v_readlane (uniform -> SGPR base, SALU addressing). Masked 4-groups.
__global__ __launch_bounds__(256) void gather_kernel(const ushort* __restrict__ y,
                                                     const int* __restrict__ off,
                                                     const int* __restrict__ csr,
                                                     const float* __restrict__ bh,
                                                     const float* __restrict__ bt,
                                                     ushort* __restrict__ f, int N) {
    int tid = threadIdx.x;
    int lane = tid & 63, wid = tid >> 6;
    const float* bp = (lane < 32) ? (bh + lane * 4) : (bt + (lane - 32) * 4);
    float4 b4 = *(const float4*)bp;
    int gw = blockIdx.x * 4 + wid;
    int nw = gridDim.x * 4;

    for (int n = gw; n < N; n += nw) {
        int e0 = off[n], e1 = off[n + 1];
        int deg = e1 - e0;
        float a0, a1, a2, a3;
        {   // self-loop row
            uint2 sv = *(const uint2*)(y + (size_t)n * 256 + lane * 4);
            a0 = __uint_as_float(sv.x << 16);
            a1 = __uint_as_float(sv.x & 0xffff0000u);
            a2 = __uint_as_float(sv.y << 16);
            a3 = __uint_as_float(sv.y & 0xffff0000u);
        }
        for (int base = 0; base < deg; base += 64) {
            int rem = deg - base;
            int iters = rem < 64 ? rem : 64;
            int sAll = csr[e0 + base + (lane < iters ? lane : iters - 1)];
            for (int i = 0; i < iters; i += 4) {
                int idx[4], s[4];
                float sc[4];
#pragma unroll
                for (int k = 0; k < 4; ++k) {
                    idx[k] = (i + k < iters) ? i + k : iters - 1;
                    sc[k] = (i + k < iters) ? 1.f : 0.f;
                }
#pragma unroll
                for (int k = 0; k < 4; ++k) s[k] = __builtin_amdgcn_readlane(sAll, idx[k]);
                uint2 v[4];
#pragma unroll
                for (int k = 0; k < 4; ++k)
                    v[k] = *(const uint2*)(y + (size_t)s[k] * 256 + lane * 4);
                // edge 0 of the group is always valid
                a0 += __uint_as_float(v[0].x << 16);
                a1 += __uint_as_float(v[0].x & 0xffff0000u);
                a2 += __uint_as_float(v[0].y << 16);
                a3 += __uint_as_float(v[0].y & 0xffff0000u);
#pragma unroll
                for (int k = 1; k < 4; ++k) {
                    a0 = fmaf(__uint_as_float(v[k].x << 16), sc[k], a0);
                    a1 = fmaf(__uint_as_float(v[k].x & 0xffff0000u), sc[k], a1);
                    a2 = fmaf(__uint_as_float(v[k].y << 16), sc[k], a2);
                    a3 = fmaf(__uint_as_float(v[k].y & 0xffff0000u), sc[k], a3);
                }
            }
        }
        float dv = rsqrtf((float)(deg + 1));
        float r0 = fmaxf(fmaf(a0, dv, b4.x), 0.f);
        float r1 = fmaxf(fmaf(a1, dv, b4.y), 0.f);
        float r2 = fmaxf(fmaf(a2, dv, b4.z), 0.f);
        float r3 = fmaxf(fmaf(a3, dv, b4.w), 0.f);
        float o0 = __shfl_xor(r0, 32);
        float o1 = __shfl_xor(r1, 32);
        float o2 = __shfl_xor(r2, 32);
        float o3 = __shfl_xor(r3, 32);
        if (lane < 32) {
            float h0 = 0.5f * (r0 + o0);
            float h1 = 0.5f * (r1 + o1);
            float h2 = 0.5f * (r2 + o2);
            float h3 = 0.5f * (r3 + o3);
            uint2 pk;
            pk.x = (uint)f2bf(h0) | ((uint)f2bf(h1) << 16);
            pk.y = (uint)f2bf(h2) | ((uint)f2bf(h3) << 16);
            *(uint2*)(f + (size_t)n * 128 + lane * 4) = pk;
        }
    }
}

// ---------- MFMA MLP: out = relu(f @ Wf + bf) @ Wc + bc ----------
__global__ __launch_bounds__(256) void mlp_kernel(const ushort* __restrict__ f,
                                                  const ushort* __restrict__ WfB,
                                                  const float* __restrict__ bfu,
                                                  const float* __restrict__ Wc,
                                                  const float* __restrict__ bc,
                                                  float* __restrict__ out, int N) {
    int tid = threadIdx.x;
    int lane = tid & 63, wid = tid >> 6;
    int rowBase = blockIdx.x * 64 + wid * 16;
    int col = lane & 15;
    int kg = lane >> 4;

    short8 bfrag[4][4];
#pragma unroll
    for (int nf = 0; nf < 4; ++nf)
#pragma unroll
        for (int kk = 0; kk < 4; ++kk)
            bfrag[nf][kk] = *(const short8*)(WfB + (size_t)(nf * 16 + col) * 128 + kk * 32 + kg * 8);

    float bfv[4], w0[4], w1[4];
#pragma unroll
    for (int nf = 0; nf < 4; ++nf) {
        int c = nf * 16 + col;
        bfv[nf] = bfu[c];
        w0[nf] = Wc[c * 2];
        w1[nf] = Wc[c * 2 + 1];
    }
    float bc0 = bc[0], bc1 = bc[1];

    int r = rowBase + col; if (r >= N) r = N - 1;
    f32x4 acc[4];
#pragma unroll
    for (int nf = 0; nf < 4; ++nf) acc[nf] = (f32x4){0.f, 0.f, 0.f, 0.f};
#pragma unroll
    for (int kk = 0; kk < 4; ++kk) {
        short8 afrag = *(const short8*)(f + (size_t)r * 128 + kk * 32 + kg * 8);
#pragma unroll
        for (int nf = 0; nf < 4; ++nf)
            acc[nf] = __builtin_amdgcn_mfma_f32_16x16x32_bf16(afrag, bfrag[nf][kk], acc[nf], 0, 0, 0);
    }

#pragma unroll
    for (int i = 0; i < 4; ++i) {
        float p0 = 0.f, p1 = 0.f;
#pragma unroll
        for (int nf = 0; nf < 4; ++nf) {
            float t = fmaxf(acc[nf][i] + bfv[nf], 0.f);
            p0 = fmaf(t, w0[nf], p0);
            p1 = fmaf(t, w1[nf], p1);
        }
#pragma unroll
        for (int d = 1; d < 16; d <<= 1) {
            p0 += __shfl_xor(p0, d);
            p1 += __shfl_xor(p1, d);
        }
        int row = rowBase + kg * 4 + i;
        if (col == 0 && row < N)
            *(float2*)(out + (size_t)row * 2) = make_float2(p0 + bc0, p1 + bc1);
    }
}

extern "C" void kernel_launch(void* const* d_in, const int* in_sizes, int n_in,
                              void* d_out, int out_size, void* d_ws, size_t ws_size,
                              hipStream_t stream) {
    const float* x  = (const float*)d_in[0];
    const int*   ei = (const int*)d_in[1];   // [2,E] int32
    const float* Wh = (const float*)d_in[3];
    const float* bh = (const float*)d_in[4];
    const float* Wt = (const float*)d_in[5];
    const float* bt = (const float*)d_in[6];
    const float* Wf = (const float*)d_in[7];
    const float* bf_ = (const float*)d_in[8];
    const float* Wc = (const float*)d_in[9];
    const float* bc = (const float*)d_in[10];
    float* out = (float*)d_out;

    int N = in_sizes[0] / IN_DIM;
    int E = in_sizes[1] / 2;
    int B = (N + 1023) / 1024;   // scan chunks

    char* w = (char*)d_ws;
    ushort* y   = (ushort*)w;  w += (size_t)N * IN_DIM * 2;          // 51.2 MB bf16
    ushort* wT  = (ushort*)w;  w += (size_t)256 * 256 * 2;
    ushort* WfB = (ushort*)w;  w += (size_t)64 * 128 * 2;
    ushort* f   = (ushort*)w;  w += (size_t)N * 128 * 2;             // 25.6 MB bf16
    float* dinv = (float*)w;   w += (size_t)N * 4;
    int*   cnt  = (int*)w;     w += (size_t)N * 4;
    int*   off  = (int*)w;     w += (((size_t)(N + 1) * 4) + 15) & ~(size_t)15;
    int*   cur  = (int*)w;     w += (size_t)N * 4;
    int*   bsum = (int*)w;     w += (((size_t)B * 4) + 15) & ~(size_t)15;
    int*   csr  = (int*)w;     w += (size_t)E * 4;

    hipMemsetAsync(cnt, 0, (size_t)N * 4, stream);
    hipMemsetAsync(cur, 0, (size_t)N * 4, stream);

    int eb = (E + 255) / 256;
    count_kernel<<<eb, 256, 0, stream>>>(ei + E, cnt, E);
    block_sum_kernel<<<B, 256, 0, stream>>>(cnt, bsum, N);
    scan_sums_kernel<<<1, 1024, 0, stream>>>(bsum, B);
    scan_out_kernel<<<B, 256, 0, stream>>>(cnt, bsum, off, dinv, N, E);
    fill_kernel<<<eb, 256, 0, stream>>>(ei, cur, off, csr, E);
    wprep_kernel<<<256, 256, 0, stream>>>(Wh, Wt, wT);
    wfb_kernel<<<64, 128, 0, stream>>>(Wf, WfB);

    gemm_kernel<<<(N + 127) / 128, 512, 0, stream>>>(x, wT, dinv, y, N);
    gather_kernel<<<2048, 256, 0, stream>>>(y, off, csr, bh, bt, f, N);
    mlp_kernel<<<(N + 63) / 64, 256, 0, stream>>>(f, WfB, bf_, Wc, bc, out, N);
}